// Round 4
// baseline (514.896 us; speedup 1.0000x reference)
//
#include <hip/hip_runtime.h>

typedef __attribute__((ext_vector_type(8))) short short8;
typedef __attribute__((ext_vector_type(4))) short short4v;
typedef __attribute__((ext_vector_type(4))) float f32x4;
typedef unsigned short u16;
typedef unsigned int u32;

__device__ __forceinline__ float bf2f(u16 h) {
    return __uint_as_float(((u32)h) << 16);
}
__device__ __forceinline__ u16 f2bf(float f) {
    u32 u = __float_as_uint(f);
    u32 r = u + 0x7fffu + ((u >> 16) & 1u);   // RNE
    return (u16)(r >> 16);
}
// pack hi16(a), hi16(b) -> (b.hi<<16)|a.hi  (truncating bf16 pack, 1 instr)
__device__ __forceinline__ u32 pack_bf(float a, float b) {
    return __builtin_amdgcn_perm(__float_as_uint(b), __float_as_uint(a), 0x07060302u);
}

__device__ __forceinline__ void async_copy16(const void* g, void* l) {
    __builtin_amdgcn_global_load_lds(
        (const __attribute__((address_space(1))) void*)g,
        (__attribute__((address_space(3))) void*)l, 16, 0, 0);
}

// ---------------------------------------------------------------------------
// fp32 -> (bf16 hi, bf16 lo) split conversion. lo = bf16(v - f(hi)).
// ---------------------------------------------------------------------------
__global__ __launch_bounds__(256) void cvt_split(
    const float* __restrict__ in, u16* __restrict__ hi, u16* __restrict__ lo, int n4)
{
    int i = blockIdx.x * 256 + threadIdx.x;
    if (i >= n4) return;
    float4 v = ((const float4*)in)[i];
    short4v h, l;
    float vv[4] = {v.x, v.y, v.z, v.w};
#pragma unroll
    for (int j = 0; j < 4; j++) {
        u16 hb = f2bf(vv[j]);
        h[j] = (short)hb;
        l[j] = (short)f2bf(vv[j] - bf2f(hb));
    }
    ((short4v*)hi)[i] = h;
    ((short4v*)lo)[i] = l;
}

// 4 router weight matrices in one launch: 64 blocks per router.
__global__ __launch_bounds__(256) void cvt_split_w4(
    const float* __restrict__ w0, const float* __restrict__ w1,
    const float* __restrict__ w2, const float* __restrict__ w3,
    u16* __restrict__ hi, u16* __restrict__ lo)
{
    const int r = blockIdx.x >> 6;
    const float* src = (r == 0) ? w0 : (r == 1) ? w1 : (r == 2) ? w2 : w3;
    int i = (blockIdx.x & 63) * 256 + threadIdx.x;
    float4 v = ((const float4*)src)[i];
    short4v h, l;
    float vv[4] = {v.x, v.y, v.z, v.w};
#pragma unroll
    for (int j = 0; j < 4; j++) {
        u16 hb = f2bf(vv[j]);
        h[j] = (short)hb;
        l[j] = (short)f2bf(vv[j] - bf2f(hb));
    }
    ((short4v*)(hi + (long)r * 65536))[i] = h;
    ((short4v*)(lo + (long)r * 65536))[i] = l;
}

__global__ __launch_bounds__(256) void cvt_bf(
    const float* __restrict__ in, u16* __restrict__ out, int n4)
{
    int i = blockIdx.x * 256 + threadIdx.x;
    if (i >= n4) return;
    float4 v = ((const float4*)in)[i];
    short4v h;
    h[0] = (short)f2bf(v.x); h[1] = (short)f2bf(v.y);
    h[2] = (short)f2bf(v.z); h[3] = (short)f2bf(v.w);
    ((short4v*)out)[i] = h;
}

// ---------------------------------------------------------------------------
// bf16 GEMM: C[M][N] = cscale * (A[M][K] * B[N][K]^T). m97 structure.
// ---------------------------------------------------------------------------
template <typename CT>
__global__ __launch_bounds__(256) void gemm_bt(
    const u16* __restrict__ A, long lda, long bsA,
    const u16* __restrict__ Bm, long ldb, long bsB,
    CT* __restrict__ C, long ldc, long bsC, int K, float cscale)
{
    __shared__ __align__(16) u16 lsA[128 * 32];
    __shared__ __align__(16) u16 lsB[128 * 32];
    const int tid = threadIdx.x;
    const int wave = tid >> 6, lane = tid & 63;
    const int quad = lane >> 4, l15 = lane & 15;
    const int wm = wave >> 1, wn = wave & 1;
    const long m0 = (long)blockIdx.x * 128, n0 = (long)blockIdx.y * 128;
    A  += (long)blockIdx.z * bsA;
    Bm += (long)blockIdx.z * bsB;
    C  += (long)blockIdx.z * bsC;
    const int srow = lane >> 2, scol = (lane & 3) * 8;

    f32x4 acc[4][4];
#pragma unroll
    for (int i = 0; i < 4; i++)
#pragma unroll
        for (int j = 0; j < 4; j++) acc[i][j] = (f32x4){0.f, 0.f, 0.f, 0.f};

    const u16* ga0 = A + (m0 + (wave * 2 + 0) * 16 + srow) * lda + scol;
    const u16* ga1 = A + (m0 + (wave * 2 + 1) * 16 + srow) * lda + scol;
    const u16* gb0 = Bm + (n0 + (wave * 2 + 0) * 16 + srow) * ldb + scol;
    const u16* gb1 = Bm + (n0 + (wave * 2 + 1) * 16 + srow) * ldb + scol;
    u16* la0 = &lsA[(wave * 2 + 0) * 512];
    u16* la1 = &lsA[(wave * 2 + 1) * 512];
    u16* lb0 = &lsB[(wave * 2 + 0) * 512];
    u16* lb1 = &lsB[(wave * 2 + 1) * 512];

    for (int kk = 0; kk < K; kk += 32) {
        async_copy16(ga0 + kk, la0);
        async_copy16(ga1 + kk, la1);
        async_copy16(gb0 + kk, lb0);
        async_copy16(gb1 + kk, lb1);
        __syncthreads();
        short8 af[4], bf[4];
#pragma unroll
        for (int mt = 0; mt < 4; mt++)
            af[mt] = *(const short8*)&lsA[(wm * 64 + mt * 16 + l15) * 32 + quad * 8];
#pragma unroll
        for (int nt = 0; nt < 4; nt++)
            bf[nt] = *(const short8*)&lsB[(wn * 64 + nt * 16 + l15) * 32 + quad * 8];
#pragma unroll
        for (int mt = 0; mt < 4; mt++)
#pragma unroll
            for (int nt = 0; nt < 4; nt++)
                acc[mt][nt] = __builtin_amdgcn_mfma_f32_16x16x32_bf16(
                    af[mt], bf[nt], acc[mt][nt], 0, 0, 0);
        __syncthreads();
    }
#pragma unroll
    for (int mt = 0; mt < 4; mt++) {
        const long rowb = m0 + wm * 64 + mt * 16 + quad * 4;
#pragma unroll
        for (int nt = 0; nt < 4; nt++) {
            const long col = n0 + wn * 64 + nt * 16 + l15;
#pragma unroll
            for (int r = 0; r < 4; r++) {
                const float v = acc[mt][nt][r] * cscale;
                if constexpr (sizeof(CT) == 2)
                    C[(rowb + r) * ldc + col] = f2bf(v);
                else
                    C[(rowb + r) * ldc + col] = v;
            }
        }
    }
}

// ---------------------------------------------------------------------------
// Fused Q/K/V^T GEMM, one dispatch. grid (8,8,24); z: mode=z>>3, b=z&7.
//  mode0: Qb[b] = hbuf[b] @ eQT[b]^T * qscale
//  mode1: Kb[b] = hbuf[b] @ eKT[b]^T
//  mode2: VTb[b] = eVT[b] @ hbuf[b]^T
// All M=N=1024, K=256, lda=ldb=256, ldc=1024, bf16 out.
// ---------------------------------------------------------------------------
__global__ __launch_bounds__(256) void gemm_qkv(
    const u16* __restrict__ hbuf, const u16* __restrict__ eQT,
    const u16* __restrict__ eKT, const u16* __restrict__ eVT,
    u16* __restrict__ Qb, u16* __restrict__ Kb, u16* __restrict__ VTb,
    float qscale)
{
    __shared__ __align__(16) u16 lsA[128 * 32];
    __shared__ __align__(16) u16 lsB[128 * 32];
    const int mode = blockIdx.z >> 3, b = blockIdx.z & 7;
    const long off256 = (long)b * 262144, off1k = (long)b * 1048576;
    const u16* A  = (mode == 2) ? (eVT + off256) : (hbuf + off256);
    const u16* Bm = (mode == 0) ? (eQT + off256) : (mode == 1) ? (eKT + off256) : (hbuf + off256);
    u16* C = ((mode == 0) ? Qb : (mode == 1) ? Kb : VTb) + off1k;
    const float cscale = (mode == 0) ? qscale : 1.0f;

    const int tid = threadIdx.x;
    const int wave = tid >> 6, lane = tid & 63;
    const int quad = lane >> 4, l15 = lane & 15;
    const int wm = wave >> 1, wn = wave & 1;
    const long m0 = (long)blockIdx.x * 128, n0 = (long)blockIdx.y * 128;
    const int srow = lane >> 2, scol = (lane & 3) * 8;

    f32x4 acc[4][4];
#pragma unroll
    for (int i = 0; i < 4; i++)
#pragma unroll
        for (int j = 0; j < 4; j++) acc[i][j] = (f32x4){0.f, 0.f, 0.f, 0.f};

    const u16* ga0 = A + (m0 + (wave * 2 + 0) * 16 + srow) * 256 + scol;
    const u16* ga1 = A + (m0 + (wave * 2 + 1) * 16 + srow) * 256 + scol;
    const u16* gb0 = Bm + (n0 + (wave * 2 + 0) * 16 + srow) * 256 + scol;
    const u16* gb1 = Bm + (n0 + (wave * 2 + 1) * 16 + srow) * 256 + scol;
    u16* la0 = &lsA[(wave * 2 + 0) * 512];
    u16* la1 = &lsA[(wave * 2 + 1) * 512];
    u16* lb0 = &lsB[(wave * 2 + 0) * 512];
    u16* lb1 = &lsB[(wave * 2 + 1) * 512];

    for (int kk = 0; kk < 256; kk += 32) {
        async_copy16(ga0 + kk, la0);
        async_copy16(ga1 + kk, la1);
        async_copy16(gb0 + kk, lb0);
        async_copy16(gb1 + kk, lb1);
        __syncthreads();
        short8 af[4], bf[4];
#pragma unroll
        for (int mt = 0; mt < 4; mt++)
            af[mt] = *(const short8*)&lsA[(wm * 64 + mt * 16 + l15) * 32 + quad * 8];
#pragma unroll
        for (int nt = 0; nt < 4; nt++)
            bf[nt] = *(const short8*)&lsB[(wn * 64 + nt * 16 + l15) * 32 + quad * 8];
#pragma unroll
        for (int mt = 0; mt < 4; mt++)
#pragma unroll
            for (int nt = 0; nt < 4; nt++)
                acc[mt][nt] = __builtin_amdgcn_mfma_f32_16x16x32_bf16(
                    af[mt], bf[nt], acc[mt][nt], 0, 0, 0);
        __syncthreads();
    }
#pragma unroll
    for (int mt = 0; mt < 4; mt++) {
        const long rowb = m0 + wm * 64 + mt * 16 + quad * 4;
#pragma unroll
        for (int nt = 0; nt < 4; nt++) {
            const long col = n0 + wn * 64 + nt * 16 + l15;
#pragma unroll
            for (int r = 0; r < 4; r++)
                C[(rowb + r) * 1024 + col] = f2bf(acc[mt][nt][r] * cscale);
        }
    }
}

// ---------------------------------------------------------------------------
// Split-K fused router logits: logits += seg-chunk, fp32 atomics.
// grid (64,2,6): z -> seg=z>>1 in {AhBh, AlBh, AhBl}, half=z&1 (K 512-chunk).
// Requires logits zero-initialized.
// ---------------------------------------------------------------------------
__global__ __launch_bounds__(256) void gemm_router(
    const u16* __restrict__ Ah, const u16* __restrict__ Al,
    const u16* __restrict__ Bh, const u16* __restrict__ Bl,
    float* __restrict__ C)
{
    __shared__ __align__(16) u16 lsA[128 * 32];
    __shared__ __align__(16) u16 lsB[128 * 32];
    const int seg = blockIdx.z >> 1;
    const int kk0 = (blockIdx.z & 1) * 512;
    const u16* A = (seg == 1) ? Al : Ah;
    const u16* B = (seg == 2) ? Bl : Bh;
    const int tid = threadIdx.x;
    const int wave = tid >> 6, lane = tid & 63;
    const int quad = lane >> 4, l15 = lane & 15;
    const int wm = wave >> 1, wn = wave & 1;
    const long m0 = (long)blockIdx.x * 128, n0 = (long)blockIdx.y * 128;
    const int srow = lane >> 2, scol = (lane & 3) * 8;
    const u16* ga = A + (m0 + (wave * 2) * 16 + srow) * 1024 + scol + kk0;
    const u16* gb = B + (n0 + (wave * 2) * 16 + srow) * 1024 + scol + kk0;
    u16* la0 = &lsA[(wave * 2 + 0) * 512];
    u16* la1 = &lsA[(wave * 2 + 1) * 512];
    u16* lb0 = &lsB[(wave * 2 + 0) * 512];
    u16* lb1 = &lsB[(wave * 2 + 1) * 512];

    f32x4 acc[4][4];
#pragma unroll
    for (int i = 0; i < 4; i++)
#pragma unroll
        for (int j = 0; j < 4; j++) acc[i][j] = (f32x4){0.f, 0.f, 0.f, 0.f};

    for (int kk = 0; kk < 512; kk += 32) {
        async_copy16(ga + kk, la0);
        async_copy16(ga + 16384 + kk, la1);
        async_copy16(gb + kk, lb0);
        async_copy16(gb + 16384 + kk, lb1);
        __syncthreads();
        short8 af[4], bf[4];
#pragma unroll
        for (int mt = 0; mt < 4; mt++)
            af[mt] = *(const short8*)&lsA[(wm * 64 + mt * 16 + l15) * 32 + quad * 8];
#pragma unroll
        for (int nt = 0; nt < 4; nt++)
            bf[nt] = *(const short8*)&lsB[(wn * 64 + nt * 16 + l15) * 32 + quad * 8];
#pragma unroll
        for (int mt = 0; mt < 4; mt++)
#pragma unroll
            for (int nt = 0; nt < 4; nt++)
                acc[mt][nt] = __builtin_amdgcn_mfma_f32_16x16x32_bf16(
                    af[mt], bf[nt], acc[mt][nt], 0, 0, 0);
        __syncthreads();
    }
#pragma unroll
    for (int mt = 0; mt < 4; mt++) {
        const long rowb = m0 + wm * 64 + mt * 16 + quad * 4;
#pragma unroll
        for (int nt = 0; nt < 4; nt++) {
            const long col = n0 + wn * 64 + nt * 16 + l15;
#pragma unroll
            for (int r = 0; r < 4; r++)
                atomicAdd(&C[(rowb + r) * 256 + col], acc[mt][nt][r]);
        }
    }
}

// ---------------------------------------------------------------------------
// Split-K h GEMM: hf32[b] += xh[b] @ scT[b]^T chunk. grid (8,2,16): b=z>>1,
// kc=z&1 (512-chunk). fp32 atomics; hf32 zero-initialized.
// ---------------------------------------------------------------------------
__global__ __launch_bounds__(256) void gemm_h(
    const u16* __restrict__ xh, const u16* __restrict__ scT, float* __restrict__ hf)
{
    __shared__ __align__(16) u16 lsA[128 * 32];
    __shared__ __align__(16) u16 lsB[128 * 32];
    const int b = blockIdx.z >> 1;
    const int kk0 = (blockIdx.z & 1) * 512;
    const u16* A = xh + (long)b * 1048576;
    const u16* Bm = scT + (long)b * 262144;
    float* C = hf + (long)b * 262144;
    const int tid = threadIdx.x;
    const int wave = tid >> 6, lane = tid & 63;
    const int quad = lane >> 4, l15 = lane & 15;
    const int wm = wave >> 1, wn = wave & 1;
    const long m0 = (long)blockIdx.x * 128, n0 = (long)blockIdx.y * 128;
    const int srow = lane >> 2, scol = (lane & 3) * 8;
    const u16* ga = A + (m0 + (wave * 2) * 16 + srow) * 1024 + scol + kk0;
    const u16* gb = Bm + (n0 + (wave * 2) * 16 + srow) * 1024 + scol + kk0;
    u16* la0 = &lsA[(wave * 2 + 0) * 512];
    u16* la1 = &lsA[(wave * 2 + 1) * 512];
    u16* lb0 = &lsB[(wave * 2 + 0) * 512];
    u16* lb1 = &lsB[(wave * 2 + 1) * 512];

    f32x4 acc[4][4];
#pragma unroll
    for (int i = 0; i < 4; i++)
#pragma unroll
        for (int j = 0; j < 4; j++) acc[i][j] = (f32x4){0.f, 0.f, 0.f, 0.f};

    for (int kk = 0; kk < 512; kk += 32) {
        async_copy16(ga + kk, la0);
        async_copy16(ga + 16384 + kk, la1);
        async_copy16(gb + kk, lb0);
        async_copy16(gb + 16384 + kk, lb1);
        __syncthreads();
        short8 af[4], bf[4];
#pragma unroll
        for (int mt = 0; mt < 4; mt++)
            af[mt] = *(const short8*)&lsA[(wm * 64 + mt * 16 + l15) * 32 + quad * 8];
#pragma unroll
        for (int nt = 0; nt < 4; nt++)
            bf[nt] = *(const short8*)&lsB[(wn * 64 + nt * 16 + l15) * 32 + quad * 8];
#pragma unroll
        for (int mt = 0; mt < 4; mt++)
#pragma unroll
            for (int nt = 0; nt < 4; nt++)
                acc[mt][nt] = __builtin_amdgcn_mfma_f32_16x16x32_bf16(
                    af[mt], bf[nt], acc[mt][nt], 0, 0, 0);
        __syncthreads();
    }
#pragma unroll
    for (int mt = 0; mt < 4; mt++) {
        const long rowb = m0 + wm * 64 + mt * 16 + quad * 4;
#pragma unroll
        for (int nt = 0; nt < 4; nt++) {
            const long col = n0 + wn * 64 + nt * 16 + l15;
#pragma unroll
            for (int r = 0; r < 4; r++)
                atomicAdd(&C[(rowb + r) * 256 + col], acc[mt][nt][r]);
        }
    }
}

// ---------------------------------------------------------------------------
// Per-token softmax over each router's 64 logits, scaled by importance,
// summed over tokens into w_raw[4][8][64] (fp32 atomics).
// ---------------------------------------------------------------------------
__global__ __launch_bounds__(128) void router_agg(
    const float* __restrict__ logits, const float* __restrict__ imp,
    float* __restrict__ w_raw)
{
    __shared__ float pref[32][257];
    const int tid = threadIdx.x;
    const int tl = tid >> 2, r = tid & 3;
    const int s = blockIdx.x * 32 + tl;
    const int b = s >> 10;
    const float* lp = logits + (long)s * 256 + r * 64;
    float v[64];
#pragma unroll
    for (int i = 0; i < 16; i++) {
        float4 f = ((const float4*)lp)[i];
        v[i * 4 + 0] = f.x; v[i * 4 + 1] = f.y;
        v[i * 4 + 2] = f.z; v[i * 4 + 3] = f.w;
    }
    float mx = v[0];
#pragma unroll
    for (int i = 1; i < 64; i++) mx = fmaxf(mx, v[i]);
    float sum = 0.f;
#pragma unroll
    for (int i = 0; i < 64; i++) { v[i] = __expf(v[i] - mx); sum += v[i]; }
    const float scale = imp[s] / sum;
#pragma unroll
    for (int i = 0; i < 64; i++) pref[tl][r * 64 + i] = v[i] * scale;
    __syncthreads();
#pragma unroll
    for (int half = 0; half < 2; half++) {
        const int idx = tid + half * 128;
        const int r2 = idx >> 6, n = idx & 63;
        float acc = 0.f;
#pragma unroll 8
        for (int t = 0; t < 32; t++) acc += pref[t][r2 * 64 + n];
        atomicAdd(&w_raw[(r2 * 8 + b) * 64 + n], acc);
    }
}

// ---------------------------------------------------------------------------
// Normalize w, top-k (k=16 router 0, else 8), renormalize.
// ---------------------------------------------------------------------------
__global__ void topk_kernel(const float* __restrict__ w_raw,
                            float* __restrict__ topw, int* __restrict__ topi)
{
    const int r = blockIdx.x >> 3, b = blockIdx.x & 7;
    const int lane = threadIdx.x;
    const int k = (r == 0) ? 16 : 8;
    float w = w_raw[(r * 8 + b) * 64 + lane];
    float tot = w;
    for (int o2 = 32; o2 >= 1; o2 >>= 1) tot += __shfl_xor(tot, o2);
    w = w / (tot + 1e-8f);
    __shared__ float tw[16];
    __shared__ int ti[16];
    float cur = w;
    float ssum = 0.f;
    for (int j = 0; j < k; j++) {
        float m = cur; int mi = lane;
        for (int o2 = 32; o2 >= 1; o2 >>= 1) {
            float om = __shfl_xor(m, o2); int oi = __shfl_xor(mi, o2);
            if (om > m || (om == m && oi < mi)) { m = om; mi = oi; }
        }
        if (lane == 0) { tw[j] = m; ti[j] = mi; }
        ssum += m;
        if (lane == mi) cur = -1e30f;
    }
    __syncthreads();
    if (lane < 16) {
        topw[(r * 8 + b) * 16 + lane] = (lane < k) ? tw[lane] / (ssum + 1e-8f) : 0.f;
        topi[(r * 8 + b) * 16 + lane] = (lane < k) ? ti[lane] : 0;
    }
}

// ---------------------------------------------------------------------------
// out[b][j][i] = sum_k w[b,k] * pool[idx[b,k]][i][j]   (transposing gather-mix)
// ---------------------------------------------------------------------------
__global__ __launch_bounds__(256) void gather_mix(
    const float* __restrict__ pool, const float* __restrict__ topw,
    const int* __restrict__ topi, u16* __restrict__ out,
    int I, int J, int k)
{
    __shared__ float tile[64][65];
    const int b = blockIdx.z;
    const long IJ = (long)I * J;
    const int i0 = blockIdx.x * 64, j0 = blockIdx.y * 64;
    const float* tw = topw + b * 16;
    const int* ti = topi + b * 16;
    const int tid = threadIdx.x;
    const int il = tid >> 2, jg = tid & 3;
    float acc[16];
#pragma unroll
    for (int m = 0; m < 16; m++) acc[m] = 0.f;
    for (int kk = 0; kk < k; kk++) {
        const float wgt = tw[kk];
        const long n = ti[kk];
        const float* src = pool + n * IJ + (long)(i0 + il) * J + j0 + jg * 16;
        float4 a0 = ((const float4*)src)[0];
        float4 a1 = ((const float4*)src)[1];
        float4 a2 = ((const float4*)src)[2];
        float4 a3 = ((const float4*)src)[3];
        acc[0] += wgt * a0.x;  acc[1] += wgt * a0.y;
        acc[2] += wgt * a0.z;  acc[3] += wgt * a0.w;
        acc[4] += wgt * a1.x;  acc[5] += wgt * a1.y;
        acc[6] += wgt * a1.z;  acc[7] += wgt * a1.w;
        acc[8] += wgt * a2.x;  acc[9] += wgt * a2.y;
        acc[10] += wgt * a2.z; acc[11] += wgt * a2.w;
        acc[12] += wgt * a3.x; acc[13] += wgt * a3.y;
        acc[14] += wgt * a3.z; acc[15] += wgt * a3.w;
    }
#pragma unroll
    for (int m = 0; m < 16; m++) tile[il][jg * 16 + m] = acc[m];
    __syncthreads();
    const int jl = tid >> 2, ig = tid & 3;
    short8 o0, o1;
#pragma unroll
    for (int m = 0; m < 8; m++) {
        o0[m] = (short)f2bf(tile[ig * 16 + m][jl]);
        o1[m] = (short)f2bf(tile[ig * 16 + 8 + m][jl]);
    }
    u16* dst = out + (long)b * IJ + (long)(j0 + jl) * I + i0 + ig * 16;
    *(short8*)dst = o0;
    *(short8*)(dst + 8) = o1;
}

// Fused expand-pool gathers (Q/K/V routers), grid (4,16,24): rr=z>>3, b=z&7.
__global__ __launch_bounds__(256) void gather_mix_e3(
    const float* __restrict__ pool, const float* __restrict__ topw,
    const int* __restrict__ topi,
    u16* __restrict__ oQ, u16* __restrict__ oK, u16* __restrict__ oV)
{
    __shared__ float tile[64][65];
    const int rr = blockIdx.z >> 3, b = blockIdx.z & 7;
    u16* out = (rr == 0) ? oQ : (rr == 1) ? oK : oV;
    const float* tw = topw + (rr + 1) * 128 + b * 16;
    const int* ti = topi + (rr + 1) * 128 + b * 16;
    const long IJ = 256L * 1024L;
    const int i0 = blockIdx.x * 64, j0 = blockIdx.y * 64;
    const int tid = threadIdx.x;
    const int il = tid >> 2, jg = tid & 3;
    float acc[16];
#pragma unroll
    for (int m = 0; m < 16; m++) acc[m] = 0.f;
    for (int kk = 0; kk < 8; kk++) {
        const float wgt = tw[kk];
        const long n = ti[kk];
        const float* src = pool + n * IJ + (long)(i0 + il) * 1024 + j0 + jg * 16;
        float4 a0 = ((const float4*)src)[0];
        float4 a1 = ((const float4*)src)[1];
        float4 a2 = ((const float4*)src)[2];
        float4 a3 = ((const float4*)src)[3];
        acc[0] += wgt * a0.x;  acc[1] += wgt * a0.y;
        acc[2] += wgt * a0.z;  acc[3] += wgt * a0.w;
        acc[4] += wgt * a1.x;  acc[5] += wgt * a1.y;
        acc[6] += wgt * a1.z;  acc[7] += wgt * a1.w;
        acc[8] += wgt * a2.x;  acc[9] += wgt * a2.y;
        acc[10] += wgt * a2.z; acc[11] += wgt * a2.w;
        acc[12] += wgt * a3.x; acc[13] += wgt * a3.y;
        acc[14] += wgt * a3.z; acc[15] += wgt * a3.w;
    }
#pragma unroll
    for (int m = 0; m < 16; m++) tile[il][jg * 16 + m] = acc[m];
    __syncthreads();
    const int jl = tid >> 2, ig = tid & 3;
    short8 o0, o1;
#pragma unroll
    for (int m = 0; m < 8; m++) {
        o0[m] = (short)f2bf(tile[ig * 16 + m][jl]);
        o1[m] = (short)f2bf(tile[ig * 16 + 8 + m][jl]);
    }
    u16* dst = out + (long)b * IJ + (long)(j0 + jl) * 256 + i0 + ig * 16;
    *(short8*)dst = o0;
    *(short8*)(dst + 8) = o1;
}

// ---------------------------------------------------------------------------
// Causal flash attention, S^T formulation, 16-row q-tiles for occupancy.
// Q (pre-scaled by 1/8*log2e), K: [B][S][D] bf16; VT: [B][D][S] bf16.
// One wave = q-tiles {pr, 63-pr} -> exactly 17 64-key iterations per wave.
// Grid 1024 blocks = 4 blocks/CU.
// ---------------------------------------------------------------------------
__global__ __launch_bounds__(256, 4) void flash_attn(
    const u16* __restrict__ Qg, const u16* __restrict__ Kg,
    const u16* __restrict__ Vt, u16* __restrict__ Og)
{
    __shared__ __align__(16) u16 plds[4][16 * 72];   // per-wave P, stride 72
    const int tid = threadIdx.x;
    const int wv = tid >> 6, lane = tid & 63;
    const int quad = lane >> 4, l15 = lane & 15;
    const int gw = blockIdx.x * 4 + wv;
    const int pr = gw & 31;
    const int bh = gw >> 5;                  // 0..127, same for all waves in block
    const int hh = bh & 15, bb = bh >> 4;
    const long SD = 1024L * 1024L;
    const u16* Qb = Qg + (long)bb * SD + hh * 64;
    const u16* Kb = Kg + (long)bb * SD + hh * 64;
    const u16* Vb = Vt + (long)bb * SD + (long)hh * 64 * 1024;
    u16* myp = plds[wv];

    for (int half = 0; half < 2; half++) {
        const int qt = half ? (63 - pr) : pr;
        const int q0 = qt * 16;

        short8 qf[2];
#pragma unroll
        for (int kb = 0; kb < 2; kb++)
            qf[kb] = *(const short8*)(Qb + (long)(q0 + l15) * 1024 + kb * 32 + quad * 8);

        f32x4 o[4];
        float mrow = -3e38f, lrow = 0.f;
#pragma unroll
        for (int nt = 0; nt < 4; nt++) o[nt] = (f32x4){0.f, 0.f, 0.f, 0.f};

        const int ntile = (q0 + 79) >> 6;    // ceil((q0+16)/64)
        for (int it = 0; it < ntile; it++) {
            const int k2 = it * 64;
            const bool last = (it == ntile - 1);
            // K loads + S^T[key][q] = K·Q^T
            f32x4 st[4];
#pragma unroll
            for (int kt = 0; kt < 4; kt++) {
                short8 kf0 = *(const short8*)(Kb + (long)(k2 + kt * 16 + l15) * 1024 + quad * 8);
                short8 kf1 = *(const short8*)(Kb + (long)(k2 + kt * 16 + l15) * 1024 + 32 + quad * 8);
                f32x4 z = (f32x4){0.f, 0.f, 0.f, 0.f};
                z = __builtin_amdgcn_mfma_f32_16x16x32_bf16(kf0, qf[0], z, 0, 0, 0);
                z = __builtin_amdgcn_mfma_f32_16x16x32_bf16(kf1, qf[1], z, 0, 0, 0);
                st[kt] = z;
            }
            // V loads (latency hidden under softmax VALU)
            short8 vf[4][2];
#pragma unroll
            for (int nt = 0; nt < 4; nt++)
#pragma unroll
                for (int kh = 0; kh < 2; kh++)
                    vf[nt][kh] = *(const short8*)(Vb + (long)(nt * 16 + l15) * 1024 + k2 + kh * 32 + quad * 8);
            // online softmax: q on lane&15, keys in regs
            if (last) {
#pragma unroll
                for (int kt = 0; kt < 4; kt++)
#pragma unroll
                    for (int r = 0; r < 4; r++)
                        if (k2 + kt * 16 + quad * 4 + r > q0 + l15)
                            st[kt][r] = -3e38f;
            }
            float cm = -3e38f;
#pragma unroll
            for (int kt = 0; kt < 4; kt++)
#pragma unroll
                for (int r = 0; r < 4; r++) cm = fmaxf(cm, st[kt][r]);
            cm = fmaxf(cm, __shfl_xor(cm, 16));
            cm = fmaxf(cm, __shfl_xor(cm, 32));
            const float mn = fmaxf(mrow, cm);
            const float am = exp2f(mrow - mn);
            mrow = mn;
            const float moff = 0.00281502f - mn;  // +log2(1+2^-9): unbias trunc pack
            float rs = 0.f;
#pragma unroll
            for (int kt = 0; kt < 4; kt++) {
                float p0 = exp2f(st[kt][0] + moff);
                float p1 = exp2f(st[kt][1] + moff);
                float p2 = exp2f(st[kt][2] + moff);
                float p3 = exp2f(st[kt][3] + moff);
                rs += (p0 + p1) + (p2 + p3);
                *(uint2*)&myp[l15 * 72 + kt * 16 + quad * 4] =
                    make_uint2(pack_bf(p0, p1), pack_bf(p2, p3));
            }
            rs += __shfl_xor(rs, 16);
            rs += __shfl_xor(rs, 32);
            lrow = lrow * am + rs;
            float av[4];
#pragma unroll
            for (int r = 0; r < 4; r++) av[r] = __shfl(am, quad * 4 + r);
            asm volatile("s_waitcnt lgkmcnt(0)" ::: "memory");
            short8 pf[2];
#pragma unroll
            for (int kh = 0; kh < 2; kh++)
                pf[kh] = *(const short8*)&myp[l15 * 72 + kh * 32 + quad * 8];
#pragma unroll
            for (int nt = 0; nt < 4; nt++) {
#pragma unroll
                for (int r = 0; r < 4; r++) o[nt][r] *= av[r];
#pragma unroll
                for (int kh = 0; kh < 2; kh++)
                    o[nt] = __builtin_amdgcn_mfma_f32_16x16x32_bf16(pf[kh], vf[nt][kh], o[nt], 0, 0, 0);
            }
        }
        // epilogue
#pragma unroll
        for (int r = 0; r < 4; r++) {
            const float li = 1.0f / __shfl(lrow, quad * 4 + r);
            const long row = q0 + quad * 4 + r;
#pragma unroll
            for (int nt = 0; nt < 4; nt++)
                Og[(long)bb * SD + row * 1024 + hh * 64 + nt * 16 + l15] =
                    f2bf(o[nt][r] * li);
        }
    }
}

// ---------------------------------------------------------------------------
extern "C" void kernel_launch(void* const* d_in, const int* in_sizes, int n_in,
                              void* d_out, int out_size, void* d_ws, size_t ws_size,
                              hipStream_t stream)
{
    const float* x   = (const float*)d_in[0];
    const float* imp = (const float*)d_in[1];
    const float* cn  = (const float*)d_in[6];
    const float* ep  = (const float*)d_in[7];
    const float* Wo  = (const float*)d_in[8];
    float* outp = (float*)d_out;
    char* ws = (char*)d_ws;

    // d_out (33.55 MB) doubles as scratch for x_hi/x_lo until the final GEMM.
    u16* xh = (u16*)d_out;                    // [8192][1024] bf16
    u16* xl = xh + 8388608;                   // [8192][1024] bf16

    u16*   Wh     = (u16*)(ws + 0);           // [4*64][1024] bf16
    u16*   Wl     = (u16*)(ws + 524288);
    u16*   Wobf   = (u16*)(ws + 1048576);     // [1024][1024] bf16
    float* w_raw  = (float*)(ws + 3145728);   // [4][8][64]
    float* topw   = (float*)(ws + 3153920);   // [4][8][16]
    int*   topi   = (int*)(ws + 3155968);     // [4][8][16]
    float* logits = (float*)(ws + 4194304);   // [8192][256] fp32; later hf32; later aout
    float* hf32   = (float*)(ws + 4194304);   // [8][1024][256] fp32 (after router_agg)
    u16*   scT    = (u16*)(ws + 12582912);    // [8][256][1024] (dead after gemm_h)
    u16*   hbuf   = (u16*)(ws + 16777216);    // [8][1024][256] (dead after qkv)
    u16*   eQT    = (u16*)(ws + 20971520);    // [8][1024][256]
    u16*   eKT    = (u16*)(ws + 25165824);
    u16*   eVT    = (u16*)(ws + 29360128);
    u16*   Qb     = (u16*)(ws + 33554432);    // [8][1024][1024]
    u16*   Kb     = (u16*)(ws + 50331648);
    u16*   VTb    = (u16*)(ws + 67108864);    // ends at 80 MB
    u16*   aout   = (u16*)(ws + 4194304);     // [8][1024][1024], after qkv all dead

    // 0) precision splits / conversions
    cvt_split<<<dim3(8192), 256, 0, stream>>>(x, xh, xl, 2097152);
    cvt_split_w4<<<dim3(256), 256, 0, stream>>>(
        (const float*)d_in[2], (const float*)d_in[3],
        (const float*)d_in[4], (const float*)d_in[5], Wh, Wl);
    cvt_bf<<<dim3(1024), 256, 0, stream>>>(Wo, Wobf, 262144);
    hipMemsetAsync(w_raw, 0, 4 * 8 * 64 * 4, stream);
    hipMemsetAsync(logits, 0, 8388608, stream);

    // 1) router logits, split-bf16 split-K (384 blocks, fp32 atomics)
    gemm_router<<<dim3(64, 2, 6), 256, 0, stream>>>(xh, xl, Wh, Wl, logits);
    // 2) softmax + importance aggregation, 3) top-k (all fp32)
    router_agg<<<dim3(256), 128, 0, stream>>>(logits, imp, w_raw);
    topk_kernel<<<dim3(32), 64, 0, stream>>>(w_raw, topw, topi);
    // 4) gathered expert mixes (fp32 pools -> bf16, stored transposed/K-contig)
    hipMemsetAsync(hf32, 0, 8388608, stream);   // logits dead; region becomes hf32
    gather_mix<<<dim3(16, 4, 8), 256, 0, stream>>>(cn, topw, topi, scT, 1024, 256, 16);
    gather_mix_e3<<<dim3(4, 16, 24), 256, 0, stream>>>(ep, topw, topi, eQT, eKT, eVT);
    // 5) h[b] = x[b] @ scT[b]^T  split-K (256 blocks, fp32 atomics) + cvt
    gemm_h<<<dim3(8, 2, 16), 256, 0, stream>>>(xh, scT, hf32);
    cvt_bf<<<dim3(2048), 256, 0, stream>>>(hf32, hbuf, 524288);
    // 6) fused Q/K/V^T GEMMs, one 1536-block dispatch.
    //    Q gets 1/sqrt(64)*log2(e) folded in for the exp2-domain flash kernel.
    gemm_qkv<<<dim3(8, 8, 24), 256, 0, stream>>>(
        hbuf, eQT, eKT, eVT, Qb, Kb, VTb, 0.180336880111f);
    // 7) causal flash attention (1024 blocks = 4/CU, balanced pairs)
    flash_attn<<<dim3(1024), 256, 0, stream>>>(Qb, Kb, VTb, aout);
    // 8) output projection: out = aout @ W_O^T (fp32 out, overwrites xh/xl scratch)
    gemm_bt<float><<<dim3(64, 8, 1), 256, 0, stream>>>(
        aout, 1024, 0, Wobf, 1024, 0, outp, 1024, 0, 1024, 1.0f);
}